// Round 1
// 239.670 us; speedup vs baseline: 1.0181x; 1.0181x over previous
//
#include <hip/hip_runtime.h>

// PhotometricLoss: fused warp + SSIM(3x3 avgpool, zero-pad) + L1 + masked mean.
// B=8, C=3, H=720, W=1280 fp32.
//
// R4: two changes vs R3 (which measured 103us kernel, 42% VALUBusy, 44% occ):
//  1. Retile RPW 12->15: grid = 21 x 12 x 8 = 2016 blocks. Combined VGPR+AGPR
//     (~96) caps residency at 4 blocks/CU = 1024 blocks; the old 2520-block
//     grid ran 2.46 "rounds" -> 38% idle tail. 2016 = 1.97 rounds (and also
//     <= 2048 = one round under an 8-block/CU cap) -> near-zero tail either way.
//  2. Gather pipeline deepened one full step: right-image gathers for row r+1
//     issue at step r (disp prefetched two rows ahead), consumed a full step
//     later -> every global load gets a full step (~350 cyc VALU) of shadow
//     instead of only the ~140-cycle emit.
// __launch_bounds__(256,4) pins the allocator at <=128 combined regs so the
// extra pipeline registers cannot halve occupancy to 8 waves/CU.

#define P_ALPHA 0.85f
#define P_C1 1e-4f
#define P_C2 9e-4f

constexpr int COLS  = 62;   // useful output columns per wave strip
constexpr int RPW   = 15;   // output rows per wave (720 = 12*4*15)
constexpr int WAVES = 4;    // waves per block

__global__ __launch_bounds__(256, 4)
void photo_loss_kernel(const float* __restrict__ disp,
                       const float* __restrict__ left,
                       const float* __restrict__ right,
                       float* __restrict__ acc,   // acc[0]=sum(photo*valid), acc[1]=sum(valid)
                       int H, int W)
{
    __shared__ float redpv[WAVES];
    __shared__ float redv[WAVES];

    const int tid  = threadIdx.x;
    const int lane = tid & 63;
    const int w    = tid >> 6;
    const int b    = blockIdx.z;
    const int col  = blockIdx.x * COLS + lane - 1;          // -1 .. W (+halo)
    const int rowStart = (blockIdx.y * WAVES + w) * RPW;

    const int planeHW = H * W;
    const float* __restrict__ dispb = disp  + b * planeHW;
    const float* __restrict__ L0 = left  + (b * 3 + 0) * planeHW;
    const float* __restrict__ L1 = left  + (b * 3 + 1) * planeHW;
    const float* __restrict__ L2 = left  + (b * 3 + 2) * planeHW;
    const float* __restrict__ R0 = right + (b * 3 + 0) * planeHW;
    const float* __restrict__ R1 = right + (b * 3 + 1) * planeHW;
    const float* __restrict__ R2 = right + (b * 3 + 2) * planeHW;

    const float wm1f = (float)(W - 1);
    const int   colC = min(max(col, 0), W - 1);             // clamped address col
    const float colv = (col >= 0 && col < W) ? 1.f : 0.f;   // column validity
    const float ocm  = (lane >= 1 && lane <= COLS && col < W) ? 1.f : 0.f;  // output mask

    // 3-row register rings (all indices compile-time after full unroll)
    float rsx[3][3], rsy[3][3], rsxx[3][3], rsyy[3][3], rsxy[3][3];
    float l1r[3], vr[3];

    float sum_pv = 0.f, sum_v = 0.f;

    // emit center row held in ring slot cs (sums over all 3 slots, order-free)
    auto emit = [&](int cs) {
        const float inv9 = 1.f / 9.f;
        float ssim_sum = 0.f;
        #pragma unroll
        for (int c = 0; c < 3; ++c) {
            float mu_x = (rsx[c][0]  + rsx[c][1]  + rsx[c][2])  * inv9;
            float mu_y = (rsy[c][0]  + rsy[c][1]  + rsy[c][2])  * inv9;
            float exx  = (rsxx[c][0] + rsxx[c][1] + rsxx[c][2]) * inv9;
            float eyy  = (rsyy[c][0] + rsyy[c][1] + rsyy[c][2]) * inv9;
            float exy  = (rsxy[c][0] + rsxy[c][1] + rsxy[c][2]) * inv9;
            float sig_x  = fmaxf(exx - mu_x * mu_x, 0.f);
            float sig_y  = fmaxf(eyy - mu_y * mu_y, 0.f);
            float sig_xy = exy - mu_x * mu_y;
            float n  = (2.f * mu_x * mu_y + P_C1) * (2.f * sig_xy + P_C2);
            float dd = (mu_x * mu_x + mu_y * mu_y + P_C1) * (sig_x + sig_y + P_C2);
            float s  = (1.f - n * __builtin_amdgcn_rcpf(dd)) * 0.5f;  // dd >= C1*C2 > 0
            s = fminf(fmaxf(s, 0.f), 1.f);
            ssim_sum += s;
        }
        float photo = P_ALPHA * (ssim_sum * (1.f / 3.f))
                    + (1.f - P_ALPHA) * (l1r[cs] * (1.f / 3.f));
        sum_pv += photo * vr[cs] * ocm;
        sum_v  += vr[cs] * ocm;
    };

    // ---- pipeline state ----
    // gC*/frC/vmC : gather results + frac + validity for the row processed THIS step
    // xC*         : left pixels of the row processed this step
    // dN          : disp of the NEXT row (arrived; used to issue next gathers)
    // offN        : clamped linear offset of the next row (left load reuses it)
    float gC0,gC1,gC2,gC3,gC4,gC5, frC, vmC;
    float xC0,xC1,xC2;
    float dN;
    int   offN;

    {   // prologue: row r0 = rowStart-1
        const int r0   = rowStart - 1;
        const int rc0  = max(r0, 0);                 // r0 >= -1, r0 < H always
        const int off0 = rc0 * W + colC;
        const float d0 = dispb[off0];
        xC0 = L0[off0]; xC1 = L1[off0]; xC2 = L2[off0];
        offN = rowStart * W + colC;                  // rowStart always in range
        dN = dispb[offN];
        // gather-issue for row r0
        const float xs  = (float)col - d0;
        const float xcl = fminf(fmaxf(xs, 0.f), wm1f);
        const float xf  = floorf(xcl);
        frC = xcl - xf;
        const int i0 = (int)xf;
        const int i1 = min(i0 + 1, W - 1);
        const int ro = rc0 * W;
        gC0 = R0[ro + i0]; gC1 = R0[ro + i1];
        gC2 = R1[ro + i0]; gC3 = R1[ro + i1];
        gC4 = R2[ro + i0]; gC5 = R2[ro + i1];
        vmC = (xs > 0.f && xs < wm1f) ? 1.f : 0.f;
    }

    #pragma unroll
    for (int j = 0; j <= RPW + 2; ++j) {
        const int s = j % 3;                    // ring slot to write (compile-time)
        const int r = rowStart - 1 + j;         // row processed this step
        if (j <= RPW + 1) {
            float gN0=0.f,gN1=0.f,gN2=0.f,gN3=0.f,gN4=0.f,gN5=0.f, frN=0.f, vmN=0.f;
            float xN0=0.f,xN1=0.f,xN2=0.f, dF=0.f;
            int   offF = 0;
            if (j <= RPW) {
                // ---- (1) gather-issue for row r+1 (dN arrived a full step ago) ----
                const float xs  = (float)col - dN;
                const float xcl = fminf(fmaxf(xs, 0.f), wm1f);
                const float xf  = floorf(xcl);
                frN = xcl - xf;
                const int i0 = (int)xf;
                const int i1 = min(i0 + 1, W - 1);
                const int ro = offN - colC;              // = clamp(r+1)*W
                gN0 = R0[ro + i0]; gN1 = R0[ro + i1];
                gN2 = R1[ro + i0]; gN3 = R1[ro + i1];
                gN4 = R2[ro + i0]; gN5 = R2[ro + i1];
                vmN = (xs > 0.f && xs < wm1f) ? 1.f : 0.f;

                // ---- (2) streaming prefetch: left(r+1) at offN, disp(r+2) ----
                xN0 = L0[offN]; xN1 = L1[offN]; xN2 = L2[offN];
                const int rc2 = min(r + 2, H - 1);       // r+2 >= 1 always
                offF = rc2 * W + colC;
                dF = dispb[offF];
            }

            // ---- (3) emit center r-2 in the load shadow (pure VALU) ----
            if (j >= 3) emit((s + 1) % 3);

            // ---- (4) process row r: consume gC (issued a FULL step ago) ----
            const float rv = (r >= 0 && r < H) ? 1.f : 0.f;
            const float m  = rv * colv;
            const float omf = 1.f - frC;
            const float y0 = (omf * gC0 + frC * gC1) * m;
            const float y1 = (omf * gC2 + frC * gC3) * m;
            const float y2 = (omf * gC4 + frC * gC5) * m;
            const float x0 = xC0 * m;
            const float x1 = xC1 * m;
            const float x2 = xC2 * m;

            float xl, xr, yl, yr;
            xl = __shfl_up(x0, 1, 64); xr = __shfl_down(x0, 1, 64);
            yl = __shfl_up(y0, 1, 64); yr = __shfl_down(y0, 1, 64);
            rsx[0][s]  = xl + x0 + xr;
            rsy[0][s]  = yl + y0 + yr;
            rsxx[0][s] = xl * xl + x0 * x0 + xr * xr;
            rsyy[0][s] = yl * yl + y0 * y0 + yr * yr;
            rsxy[0][s] = xl * yl + x0 * y0 + xr * yr;

            xl = __shfl_up(x1, 1, 64); xr = __shfl_down(x1, 1, 64);
            yl = __shfl_up(y1, 1, 64); yr = __shfl_down(y1, 1, 64);
            rsx[1][s]  = xl + x1 + xr;
            rsy[1][s]  = yl + y1 + yr;
            rsxx[1][s] = xl * xl + x1 * x1 + xr * xr;
            rsyy[1][s] = yl * yl + y1 * y1 + yr * yr;
            rsxy[1][s] = xl * yl + x1 * y1 + xr * yr;

            xl = __shfl_up(x2, 1, 64); xr = __shfl_down(x2, 1, 64);
            yl = __shfl_up(y2, 1, 64); yr = __shfl_down(y2, 1, 64);
            rsx[2][s]  = xl + x2 + xr;
            rsy[2][s]  = yl + y2 + yr;
            rsxx[2][s] = xl * xl + x2 * x2 + xr * xr;
            rsyy[2][s] = yl * yl + y2 * y2 + yr * yr;
            rsxy[2][s] = xl * yl + x2 * y2 + xr * yr;

            l1r[s] = fabsf(x0 - y0) + fabsf(x1 - y1) + fabsf(x2 - y2);
            vr[s]  = vmC;

            // rotate pipeline
            if (j <= RPW) {
                gC0 = gN0; gC1 = gN1; gC2 = gN2; gC3 = gN3; gC4 = gN4; gC5 = gN5;
                frC = frN; vmC = vmN;
                xC0 = xN0; xC1 = xN1; xC2 = xN2;
                dN = dF; offN = offF;
            }
        } else {
            emit((s + 1) % 3);                  // final center rowStart+RPW-1
        }
    }

    // wave reduce (64 lanes) then cross-wave via tiny LDS
    #pragma unroll
    for (int off = 32; off > 0; off >>= 1) {
        sum_pv += __shfl_down(sum_pv, off, 64);
        sum_v  += __shfl_down(sum_v,  off, 64);
    }
    if (lane == 0) { redpv[w] = sum_pv; redv[w] = sum_v; }
    __syncthreads();
    if (tid == 0) {
        atomicAdd(&acc[0], redpv[0] + redpv[1] + redpv[2] + redpv[3]);
        atomicAdd(&acc[1], redv[0]  + redv[1]  + redv[2]  + redv[3]);
    }
}

__global__ void photo_loss_finalize(const float* __restrict__ acc,
                                    float* __restrict__ out)
{
    out[0] = acc[0] / fmaxf(acc[1], 1.f);
}

extern "C" void kernel_launch(void* const* d_in, const int* in_sizes, int n_in,
                              void* d_out, int out_size, void* d_ws, size_t ws_size,
                              hipStream_t stream)
{
    const float* disp  = (const float*)d_in[0];
    const float* left  = (const float*)d_in[1];
    const float* right = (const float*)d_in[2];
    float* out = (float*)d_out;
    float* acc = (float*)d_ws;

    const int B = 8, H = 720, W = 1280;

    hipMemsetAsync(acc, 0, 2 * sizeof(float), stream);

    // x: 21 strips of 62 cols; y: 720 / (4 waves * 15 rows) = 12; z: batch
    // 21*12*8 = 2016 blocks: 1.97 rounds at a 1024-block residency cap
    // (combined-reg limited), or 0.98 rounds at a 2048-block cap.
    dim3 grid((W + COLS - 1) / COLS, H / (WAVES * RPW), B);
    dim3 block(256);
    photo_loss_kernel<<<grid, block, 0, stream>>>(disp, left, right, acc, H, W);
    photo_loss_finalize<<<1, 1, 0, stream>>>(acc, out);
}